// Round 1
// baseline (11466.225 us; speedup 1.0000x reference)
//
#include <hip/hip_runtime.h>
#include <hip/hip_cooperative_groups.h>
#include <math.h>

namespace cg = cooperative_groups;

// ---------------- problem constants ----------------
#define K_BEAM  10
#define V_SZ    50257
#define E_SZ    128
#define H1_SZ   128
#define H2_SZ   64
#define Q_SZ    64
#define T_SZ    2048
#define MAXLEN  30
#define SEQ_LEN 31
#define SOS_TOK 1
#define EOS_TOK 2

#define NBLK 256            // grid blocks (1 per CU, co-resident via cooperative launch)
#define NTHR 512            // threads per block (8 waves)
#define VC   197            // ceil(V_SZ / NBLK); last block vn = 22

// ---------------- workspace layout (float indices; f64 slots at even idx) ----
#define ST_A_F   0          // double[4480]: h1[10][128],c1[10][128],h2[10][64],c2,ctx
#define ST_B_F   8960
#define SD_H1    0
#define SD_C1    1280
#define SD_H2    2560
#define SD_C2    3200
#define SD_CTX   3840
#define META_A_F 17920      // SC double[10](@0), FIN i32[10](@20), PREV i32[10](@30), SEQ i32[10][31](@40)
#define META_B_F 18272
#define M_SC     0
#define M_FIN    20
#define M_PREV   30
#define M_SEQ    40
#define XS_F     19936      // double[10][128]: {h2[64], ctx[64]} per beam (phase A -> phase B)
#define LSEM_F   83136      // double[256][10]
#define LSES_F   88256      // double[256][10]
#define CANDV_F  93376      // float[256][10][10]
#define CANDI_F  118976     // int[256][10][10]
#define B10V_F   144576     // double[10][10] per-beam top10 values
#define B10F_F   144776     // int[10][10]   per-beam top10 flat indices

// ---------------- wave helpers ----------------
__device__ __forceinline__ void wave_merge_ms_d(double& m, double& s) {
  #pragma unroll
  for (int off = 32; off > 0; off >>= 1) {
    double om = __shfl_down(m, off, 64);
    double os = __shfl_down(s, off, 64);
    double nm = fmax(m, om);
    s = s * exp(m - nm) + os * exp(om - nm);
    m = nm;
  }
}
__device__ __forceinline__ void wave_argmax_f(float& v, int& i) {
  #pragma unroll
  for (int off = 32; off > 0; off >>= 1) {
    float ov = __shfl_down(v, off, 64);
    int   oi = __shfl_down(i, off, 64);
    if (ov > v || (ov == v && oi < i)) { v = ov; i = oi; }
  }
}

// merge 100 per-beam candidates (global B10V/B10F) -> global top-10 picks.
// Executed by wave 0 of a block. Order: (value desc, flat asc). Matches old msel.
__device__ __forceinline__ void merge100(const float* ws, double* selv, int* self_, int lane) {
  const double* bv = (const double*)(ws + B10V_F);
  const int*    bf = (const int*)(ws + B10F_F);
  double av = (lane < 100) ? bv[lane] : -1e302;
  int    af = (lane < 100) ? bf[lane] : 0x7fffffff;
  const int c1 = lane + 64;
  double cv = (c1 < 100) ? bv[c1] : -1e302;
  int    cf = (c1 < 100) ? bf[c1] : 0x7fffffff;
  #pragma unroll
  for (int pick = 0; pick < 10; ++pick) {
    bool tb = (cv > av) || (cv == av && cf < af);
    double lv = tb ? cv : av;
    int    lf = tb ? cf : af;
    int    ls = tb ? c1 : lane;
    #pragma unroll
    for (int off = 32; off > 0; off >>= 1) {
      double ov = __shfl_down(lv, off, 64);
      int    of = __shfl_down(lf, off, 64);
      int    os = __shfl_down(ls, off, 64);
      if (ov > lv || (ov == lv && of < lf)) { lv = ov; lf = of; ls = os; }
    }
    ls = __shfl(ls, 0, 64);
    if (lane == 0) { selv[pick] = lv; self_[pick] = lf; }
    if (ls == lane) { av = -1e302; af = 0x7fffffff; }   // destructively exclude
    if (ls == c1)   { cv = -1e302; cf = 0x7fffffff; }
  }
}

// ---------------- the persistent cooperative kernel ----------------
__global__ __launch_bounds__(NTHR, 2) void beam_fused(
    float* __restrict__ ws, float* __restrict__ out,
    const float* __restrict__ enc_key, const float* __restrict__ enc_values,
    const float* __restrict__ maskp, const float* __restrict__ embedding,
    const float* __restrict__ W_ih1, const float* __restrict__ W_hh1,
    const float* __restrict__ b_ih1, const float* __restrict__ b_hh1,
    const float* __restrict__ W_ih2, const float* __restrict__ W_hh2,
    const float* __restrict__ b_ih2, const float* __restrict__ b_hh2,
    const float* __restrict__ Wq, const float* __restrict__ bq,
    const float* __restrict__ Wc, const float* __restrict__ bc)
{
  cg::grid_group grid = cg::this_grid();
  const int tid  = threadIdx.x;
  const int blk  = blockIdx.x;
  const int lane = tid & 63;
  const int wv   = tid >> 6;

  // ---- shared memory (union of all phases; ~52 KB, fine at 1 block/CU) ----
  __shared__ double sh_e[T_SZ];        // energies -> attention weights
  __shared__ double sh_red[NTHR];      // block reductions
  __shared__ double sh_xin[192];
  __shared__ double sh_h1p[128];
  __shared__ double sh_g1[512];
  __shared__ double sh_h1n[128];
  __shared__ double sh_h2p[64];
  __shared__ double sh_gt2[256];
  __shared__ double sh_h2n[64];
  __shared__ double sh_qs[64];
  __shared__ double sh_xs[K_BEAM*128]; // phase B input
  __shared__ float  sh_lg[VC*K_BEAM];  // phase B logits
  __shared__ double sh_selv[10];       // global picks (values)
  __shared__ int    sh_self[10];       // global picks (flat)
  __shared__ double sh_wtv[80];        // SEL: per-wave top10
  __shared__ int    sh_wti[80];
  __shared__ double sh_base;
  __shared__ double sh_sc;
  __shared__ int    sh_pb, sh_tok;
  __shared__ int    sh_seqF[K_BEAM*SEQ_LEN];
  __shared__ int    sh_fpb[K_BEAM], sh_ftok[K_BEAM];

  // ---- init: each of blocks 0..9 initializes its own beam's state (block-local, no grid sync needed)
  if (blk < K_BEAM) {
    double* SA = (double*)(ws + ST_A_F);
    if (tid < 128) { SA[SD_H1 + blk*H1_SZ + tid] = 0.0; SA[SD_C1 + blk*H1_SZ + tid] = 0.0; }
    if (tid >= 128 && tid < 192) {
      int i2 = tid - 128;
      SA[SD_H2 + blk*H2_SZ + i2] = 0.0; SA[SD_C2 + blk*H2_SZ + i2] = 0.0;
      SA[SD_CTX + blk*Q_SZ + i2] = 0.0;
    }
    float* mA = ws + META_A_F;
    if (tid == 0) {
      ((double*)(mA + M_SC))[blk] = 0.0;
      ((int*)(mA + M_FIN))[blk] = 0;
      ((int*)(mA + M_PREV))[blk] = SOS_TOK;
    }
    if (tid < SEQ_LEN) ((int*)(mA + M_SEQ))[blk*SEQ_LEN + tid] = SOS_TOK;
  }

  for (int step = 0; step < MAXLEN; ++step) {
    // =================== PHASE A: blocks 0..9 (beam b = blk) ===================
    if (blk < K_BEAM) {
      const int b = blk;
      const int par = step & 1;
      const double* S = (const double*)(ws + (par == 0 ? ST_A_F : ST_B_F));
      double*       D = (double*)(ws + (par == 0 ? ST_B_F : ST_A_F));
      const float* msrc = ws + (par == 0 ? META_A_F : META_B_F);
      float*       mdst = ws + (par == 0 ? META_B_F : META_A_F);
      __syncthreads();

      // ---- decode pick for this beam ----
      if (step == 0) {
        if (tid == 0) {
          int tok = ((const int*)(msrc + M_PREV))[b];
          double sc = ((const double*)(msrc + M_SC))[b];
          int fin = ((const int*)(msrc + M_FIN))[b];
          sh_pb = b; sh_tok = tok; sh_sc = sc;
          ((double*)(mdst + M_SC))[b] = sc;
          ((int*)(mdst + M_FIN))[b] = fin;
          ((int*)(mdst + M_PREV))[b] = tok;
        }
      } else {
        if (wv == 0) merge100(ws, sh_selv, sh_self, lane);  // redundant in 10 blocks; saves a grid sync
        __syncthreads();
        if (tid == 0) {
          int f = sh_self[b];
          int pb = f / V_SZ; int tok = f - pb*V_SZ;
          pb = min(max(pb, 0), K_BEAM - 1); tok = min(max(tok, 0), V_SZ - 1);
          double sc = sh_selv[b];
          int fin = ((const int*)(msrc + M_FIN))[pb] | (tok == EOS_TOK);
          sh_pb = pb; sh_tok = tok; sh_sc = sc;
          ((double*)(mdst + M_SC))[b] = sc;
          ((int*)(mdst + M_FIN))[b] = fin;
          ((int*)(mdst + M_PREV))[b] = tok;
        }
      }
      __syncthreads();
      const int pb = sh_pb, tok = sh_tok;

      // seq copy + input staging
      if (tid < SEQ_LEN) {
        int v = ((const int*)(msrc + M_SEQ))[pb*SEQ_LEN + tid];
        if (step > 0 && tid == step) v = tok;
        ((int*)(mdst + M_SEQ))[b*SEQ_LEN + tid] = v;
      }
      if (tid < 128)                     sh_xin[tid] = (double)embedding[(size_t)tok*E_SZ + tid];
      else if (tid < 192)                sh_xin[tid] = S[SD_CTX + pb*Q_SZ + (tid - 128)];
      if (tid >= 256 && tid < 384)       sh_h1p[tid - 256] = S[SD_H1 + pb*H1_SZ + (tid - 256)];
      __syncthreads();

      // ---- LSTM1 gates: 512 rows, 1 row/thread ----
      {
        const int r = tid;
        double acc = (double)b_ih1[r] + (double)b_hh1[r];
        const float4* wi = (const float4*)(W_ih1 + (size_t)r*192);
        #pragma unroll 8
        for (int j = 0; j < 48; ++j) {
          float4 w = wi[j];
          acc += (double)w.x*sh_xin[4*j]   + (double)w.y*sh_xin[4*j+1]
               + (double)w.z*sh_xin[4*j+2] + (double)w.w*sh_xin[4*j+3];
        }
        const float4* wh = (const float4*)(W_hh1 + (size_t)r*128);
        #pragma unroll 8
        for (int j = 0; j < 32; ++j) {
          float4 w = wh[j];
          acc += (double)w.x*sh_h1p[4*j]   + (double)w.y*sh_h1p[4*j+1]
               + (double)w.z*sh_h1p[4*j+2] + (double)w.w*sh_h1p[4*j+3];
        }
        sh_g1[r] = acc;
      }
      __syncthreads();
      // LSTM1 activation
      if (tid < 128) {
        double ig = 1.0/(1.0 + exp(-sh_g1[tid]));
        double fg = 1.0/(1.0 + exp(-sh_g1[128 + tid]));
        double gg = tanh(sh_g1[256 + tid]);
        double og = 1.0/(1.0 + exp(-sh_g1[384 + tid]));
        double c = fg * S[SD_C1 + pb*H1_SZ + tid] + ig*gg;
        double h = og * tanh(c);
        D[SD_C1 + b*H1_SZ + tid] = c; D[SD_H1 + b*H1_SZ + tid] = h;
        sh_h1n[tid] = h;
      }
      if (tid >= 128 && tid < 192) sh_h2p[tid - 128] = S[SD_H2 + pb*H2_SZ + (tid - 128)];
      __syncthreads();

      // ---- LSTM2 gates: 256 rows ----
      if (tid < 256) {
        const int r = tid;
        double acc = (double)b_ih2[r] + (double)b_hh2[r];
        const float4* wi2 = (const float4*)(W_ih2 + (size_t)r*128);
        #pragma unroll 8
        for (int j = 0; j < 32; ++j) {
          float4 w = wi2[j];
          acc += (double)w.x*sh_h1n[4*j]   + (double)w.y*sh_h1n[4*j+1]
               + (double)w.z*sh_h1n[4*j+2] + (double)w.w*sh_h1n[4*j+3];
        }
        const float4* wh2 = (const float4*)(W_hh2 + (size_t)r*64);
        #pragma unroll 8
        for (int j = 0; j < 16; ++j) {
          float4 w = wh2[j];
          acc += (double)w.x*sh_h2p[4*j]   + (double)w.y*sh_h2p[4*j+1]
               + (double)w.z*sh_h2p[4*j+2] + (double)w.w*sh_h2p[4*j+3];
        }
        sh_gt2[r] = acc;
      }
      __syncthreads();
      // LSTM2 activation + h2 out
      if (tid < 64) {
        double ig = 1.0/(1.0 + exp(-sh_gt2[tid]));
        double fg = 1.0/(1.0 + exp(-sh_gt2[64 + tid]));
        double gg = tanh(sh_gt2[128 + tid]);
        double og = 1.0/(1.0 + exp(-sh_gt2[192 + tid]));
        double c = fg * S[SD_C2 + pb*H2_SZ + tid] + ig*gg;
        double h = og * tanh(c);
        D[SD_C2 + b*H2_SZ + tid] = c; D[SD_H2 + b*H2_SZ + tid] = h;
        sh_h2n[tid] = h;
        ((double*)(ws + XS_F))[b*128 + tid] = h;
      }
      __syncthreads();
      // q
      if (tid < 64) {
        double acc = (double)bq[tid];
        const float4* wr = (const float4*)(Wq + (size_t)tid*64);
        #pragma unroll
        for (int j = 0; j < 16; ++j) {
          float4 w = wr[j];
          acc += (double)w.x*sh_h2n[4*j]   + (double)w.y*sh_h2n[4*j+1]
               + (double)w.z*sh_h2n[4*j+2] + (double)w.w*sh_h2n[4*j+3];
        }
        sh_qs[tid] = acc;
      }
      __syncthreads();

      // ---- attention: energies, softmax, masked renorm, ctx ----
      double lmax = -1e300;
      for (int t = tid; t < T_SZ; t += NTHR) {
        const float4* kr = (const float4*)(enc_key + (size_t)t*64);
        double e = 0.0;
        #pragma unroll
        for (int j = 0; j < 16; ++j) {
          float4 k2 = kr[j];
          e += (double)k2.x*sh_qs[4*j]   + (double)k2.y*sh_qs[4*j+1]
             + (double)k2.z*sh_qs[4*j+2] + (double)k2.w*sh_qs[4*j+3];
        }
        sh_e[t] = e;
        lmax = fmax(lmax, e);
      }
      sh_red[tid] = lmax; __syncthreads();
      for (int s2 = 256; s2 > 0; s2 >>= 1) { if (tid < s2) sh_red[tid] = fmax(sh_red[tid], sh_red[tid + s2]); __syncthreads(); }
      const double mx = sh_red[0]; __syncthreads();
      double lsum = 0.0;
      for (int t = tid; t < T_SZ; t += NTHR) lsum += exp(sh_e[t] - mx);
      sh_red[tid] = lsum; __syncthreads();
      for (int s2 = 256; s2 > 0; s2 >>= 1) { if (tid < s2) sh_red[tid] += sh_red[tid + s2]; __syncthreads(); }
      const double Ss = sh_red[0]; __syncthreads();
      double lms = 0.0;
      for (int t = tid; t < T_SZ; t += NTHR) {
        double w = (double)maskp[t] * (exp(sh_e[t] - mx) / Ss);
        sh_e[t] = w;
        lms += w;
      }
      sh_red[tid] = lms; __syncthreads();
      for (int s2 = 256; s2 > 0; s2 >>= 1) { if (tid < s2) sh_red[tid] += sh_red[tid + s2]; __syncthreads(); }
      const double ms = fmax(sh_red[0], 2e-30); __syncthreads();
      {
        const int v = tid & 63, g = tid >> 6;   // 8 groups of 64
        double acc = 0.0;
        for (int k = 0; k < 256; ++k) {
          int t = g + 8*k;
          acc += sh_e[t] * (double)enc_values[(size_t)t*64 + v];
        }
        sh_red[tid] = acc;
      }
      __syncthreads();
      if (tid < 64) {
        double cv = 0.0;
        #pragma unroll
        for (int g = 0; g < 8; ++g) cv += sh_red[g*64 + tid];
        cv /= ms;
        D[SD_CTX + b*Q_SZ + tid] = cv;
        ((double*)(ws + XS_F))[b*128 + 64 + tid] = cv;
      }
    }
    __threadfence();
    grid.sync();

    // =================== PHASE B: all 256 blocks — logits, LSE, block top-10 ===================
    {
      const int v0 = blk * VC;
      const int vn = min(VC, V_SZ - v0);
      __syncthreads();
      for (int i2 = tid; i2 < K_BEAM*128; i2 += NTHR) sh_xs[i2] = ((const double*)(ws + XS_F))[i2];
      __syncthreads();
      if (tid < vn) {
        const int vl = tid;
        const float4* wr = (const float4*)(Wc + (size_t)(v0 + vl)*128);
        double acc[K_BEAM];
        #pragma unroll
        for (int b2 = 0; b2 < K_BEAM; ++b2) acc[b2] = 0.0;
        for (int j = 0; j < 32; ++j) {
          float4 w = wr[j];
          double w0 = (double)w.x, w1 = (double)w.y, w2 = (double)w.z, w3 = (double)w.w;
          #pragma unroll
          for (int b2 = 0; b2 < K_BEAM; ++b2) acc[b2] += w0 * sh_xs[b2*128 + 4*j];
          #pragma unroll
          for (int b2 = 0; b2 < K_BEAM; ++b2) acc[b2] += w1 * sh_xs[b2*128 + 4*j + 1];
          #pragma unroll
          for (int b2 = 0; b2 < K_BEAM; ++b2) acc[b2] += w2 * sh_xs[b2*128 + 4*j + 2];
          #pragma unroll
          for (int b2 = 0; b2 < K_BEAM; ++b2) acc[b2] += w3 * sh_xs[b2*128 + 4*j + 3];
        }
        double bcv = (double)bc[v0 + vl];
        #pragma unroll
        for (int b2 = 0; b2 < K_BEAM; ++b2) sh_lg[vl*K_BEAM + b2] = (float)(acc[b2] + bcv);
      }
      __syncthreads();

      double* lse_m = (double*)(ws + LSEM_F);
      double* lse_s = (double*)(ws + LSES_F);
      float*  cvv   = ws + CANDV_F;
      int*    cii   = (int*)(ws + CANDI_F);
      for (int b2 = wv; b2 < K_BEAM; b2 += 8) {
        double m = -1e300, s = 0.0;
        for (int vl = lane; vl < vn; vl += 64) {
          double val = (double)sh_lg[vl*K_BEAM + b2];
          double nm = fmax(m, val);
          s = s*exp(m - nm) + exp(val - nm); m = nm;
        }
        wave_merge_ms_d(m, s);
        if (lane == 0) { lse_m[blk*K_BEAM + b2] = m; lse_s[blk*K_BEAM + b2] = s; }
        // top-10 with destructive exclusion (cells of beam b2 owned exclusively by this wave)
        #pragma unroll
        for (int pick = 0; pick < 10; ++pick) {
          float bv = -3e38f; int bi = 0x7ffffff0;
          for (int vl = lane; vl < vn; vl += 64) {
            float val = sh_lg[vl*K_BEAM + b2];
            if (val > bv || (val == bv && vl < bi)) { bv = val; bi = vl; }
          }
          wave_argmax_f(bv, bi);
          bv = __shfl(bv, 0, 64); bi = __shfl(bi, 0, 64);
          int wi = min(max(bi, 0), vn - 1);
          if (lane == 0) {
            cvv[(blk*K_BEAM + b2)*10 + pick] = bv;
            cii[(blk*K_BEAM + b2)*10 + pick] = v0 + wi;
          }
          if (bi >= 0 && bi < vn && (bi & 63) == lane) sh_lg[bi*K_BEAM + b2] = -3e38f;
        }
      }
    }
    __threadfence();
    grid.sync();

    // =================== PHASE SEL: blocks 0..9, beam j = blk — per-beam top-10 of 2560 ===================
    if (blk < K_BEAM) {
      const int j = blk;
      const int par = step & 1;
      const float* mcur = ws + (par == 0 ? META_B_F : META_A_F);   // META written this step
      const double scj = ((const double*)(mcur + M_SC))[j];
      const int finj   = ((const int*)(mcur + M_FIN))[j];
      const bool masked = finj || (step == 0 && j > 0);

      if (wv == 0) {
        double m = -1e300, s = 0.0;
        for (int c = lane; c < NBLK; c += 64) {
          double mc  = ((const double*)(ws + LSEM_F))[c*K_BEAM + j];
          double sc2 = ((const double*)(ws + LSES_F))[c*K_BEAM + j];
          double nm = fmax(m, mc);
          s = s*exp(m - nm) + sc2*exp(mc - nm); m = nm;
        }
        wave_merge_ms_d(m, s);
        if (lane == 0) sh_base = scj - (m + log(s));
      }
      __syncthreads();
      const double base = sh_base;

      // each wave: local top-10 over its 320 candidates (5 per lane, in registers)
      float rv[5]; int ri[5];
      #pragma unroll
      for (int k = 0; k < 5; ++k) {
        int c = wv*320 + 64*k + lane;
        int blkc = c / 10, p = c - blkc*10;
        int idx = (blkc*K_BEAM + j)*10 + p;
        rv[k] = (ws + CANDV_F)[idx];
        ri[k] = ((const int*)(ws + CANDI_F))[idx];
      }
      #pragma unroll
      for (int pick = 0; pick < 10; ++pick) {
        double lv = -1e301; int li = 0x7ffffff0;
        if (!masked) {
          #pragma unroll
          for (int k = 0; k < 5; ++k) {
            double val = base + (double)rv[k];
            int v = ri[k];
            if (val > lv || (val == lv && v < li)) { lv = val; li = v; }
          }
        }
        #pragma unroll
        for (int off = 32; off > 0; off >>= 1) {
          double ov = __shfl_down(lv, off, 64);
          int    oi = __shfl_down(li, off, 64);
          if (ov > lv || (ov == lv && oi < li)) { lv = ov; li = oi; }
        }
        lv = __shfl(lv, 0, 64); li = __shfl(li, 0, 64);
        if (!masked) {
          #pragma unroll
          for (int k = 0; k < 5; ++k) if (ri[k] == li) rv[k] = -3e38f;  // destructive exclude
        }
        if (lane == 0) { sh_wtv[wv*10 + pick] = lv; sh_wti[wv*10 + pick] = li; }
      }
      __syncthreads();

      // wave 0: merge 80 -> 10, write global B10
      if (wv == 0) {
        double av = (lane < 80) ? sh_wtv[lane] : -1e305;
        int    ai = (lane < 80) ? sh_wti[lane] : 0x7fffffff;
        const int c1 = lane + 64;
        double bv2 = (c1 < 80) ? sh_wtv[c1] : -1e305;
        int    bi2 = (c1 < 80) ? sh_wti[c1] : 0x7fffffff;
        #pragma unroll
        for (int pick = 0; pick < 10; ++pick) {
          bool tb = (bv2 > av) || (bv2 == av && bi2 < ai);
          double lv = tb ? bv2 : av;
          int    li = tb ? bi2 : ai;
          int    ls = tb ? c1  : lane;
          #pragma unroll
          for (int off = 32; off > 0; off >>= 1) {
            double ov = __shfl_down(lv, off, 64);
            int    oi = __shfl_down(li, off, 64);
            int    os = __shfl_down(ls, off, 64);
            if (ov > lv || (ov == lv && oi < li)) { lv = ov; li = oi; ls = os; }
          }
          ls = __shfl(ls, 0, 64);
          if (ls == lane) { av  = -1e305; ai  = 0x7fffffff; }
          if (ls == c1)   { bv2 = -1e305; bi2 = 0x7fffffff; }
          if (lane == 0) {
            double outv; int outf;
            if (finj) {
              outv = (pick == 0) ? scj : -1e301;
              outf = (pick == 0) ? (j*V_SZ + EOS_TOK) : 0x7ffffff0;
            } else if (step == 0 && j > 0) {
              outv = -1e301; outf = 0x7ffffff0;
            } else {
              outv = lv;
              outf = j*V_SZ + min(max(li, 0), V_SZ - 1);
            }
            ((double*)(ws + B10V_F))[j*10 + pick] = outv;
            ((int*)(ws + B10F_F))[j*10 + pick] = outf;
          }
        }
      }
    }
    __threadfence();
    grid.sync();
  } // step loop

  // =================== FINAL: block 0 — last selection + gather + output ===================
  if (blk == 0) {
    __syncthreads();
    if (wv == 0) merge100(ws, sh_selv, sh_self, lane);
    __syncthreads();
    const float* mA = ws + META_A_F;              // dst of step 29 (odd -> A)
    const int* seqA = (const int*)(mA + M_SEQ);
    if (tid < K_BEAM) {
      int f = sh_self[tid];
      int pb = f / V_SZ, tk2 = f - pb*V_SZ;
      sh_fpb[tid]  = min(max(pb, 0), K_BEAM - 1);
      sh_ftok[tid] = min(max(tk2, 0), V_SZ - 1);
    }
    __syncthreads();
    for (int t = tid; t < K_BEAM*SEQ_LEN; t += NTHR) {
      int j2 = t / SEQ_LEN, p = t - j2*SEQ_LEN;
      sh_seqF[t] = (p == MAXLEN) ? sh_ftok[j2] : seqA[sh_fpb[j2]*SEQ_LEN + p];
    }
    __syncthreads();
    if (tid < K_BEAM) {
      int first = -1;
      for (int p = 1; p <= MAXLEN; ++p)
        if (sh_seqF[tid*SEQ_LEN + p] == EOS_TOK) { first = p - 1; break; }
      double len = (first >= 0) ? (double)(first + 2) : (double)(MAXLEN + 2);
      double scv = sh_selv[tid];
      out[K_BEAM*SEQ_LEN + tid] = (float)scv;
      out[K_BEAM*SEQ_LEN + K_BEAM + tid] = (float)(scv / pow(len, 1.2));
    }
    for (int t = tid; t < K_BEAM*SEQ_LEN; t += NTHR) out[t] = (float)sh_seqF[t];
  }
}

// ---------------- host ----------------
extern "C" void kernel_launch(void* const* d_in, const int* in_sizes, int n_in,
                              void* d_out, int out_size, void* d_ws, size_t ws_size,
                              hipStream_t stream) {
  (void)in_sizes; (void)n_in; (void)out_size; (void)ws_size;
  const float* enc_key    = (const float*)d_in[0];
  const float* enc_values = (const float*)d_in[1];
  const float* maskp      = (const float*)d_in[2];
  const float* embedding  = (const float*)d_in[3];
  const float* W_ih1      = (const float*)d_in[4];
  const float* W_hh1      = (const float*)d_in[5];
  const float* b_ih1      = (const float*)d_in[6];
  const float* b_hh1      = (const float*)d_in[7];
  const float* W_ih2      = (const float*)d_in[8];
  const float* W_hh2      = (const float*)d_in[9];
  const float* b_ih2      = (const float*)d_in[10];
  const float* b_hh2      = (const float*)d_in[11];
  const float* Wq         = (const float*)d_in[12];
  const float* bq         = (const float*)d_in[13];
  const float* Wc         = (const float*)d_in[14];
  const float* bc         = (const float*)d_in[15];
  float* ws  = (float*)d_ws;
  float* out = (float*)d_out;

  void* args[] = { (void*)&ws, (void*)&out,
                   (void*)&enc_key, (void*)&enc_values, (void*)&maskp, (void*)&embedding,
                   (void*)&W_ih1, (void*)&W_hh1, (void*)&b_ih1, (void*)&b_hh1,
                   (void*)&W_ih2, (void*)&W_hh2, (void*)&b_ih2, (void*)&b_hh2,
                   (void*)&Wq, (void*)&bq, (void*)&Wc, (void*)&bc };
  hipLaunchCooperativeKernel((const void*)beam_fused, dim3(NBLK), dim3(NTHR), args, 0, stream);
}

// Round 2
// 8062.991 us; speedup vs baseline: 1.4221x; 1.4221x over previous
//
#include <hip/hip_runtime.h>
#include <math.h>

// ---------------- problem constants ----------------
#define K_BEAM  10
#define V_SZ    50257
#define E_SZ    128
#define H1_SZ   128
#define H2_SZ   64
#define Q_SZ    64
#define T_SZ    2048
#define MAXLEN  30
#define SEQ_LEN 31
#define SOS_TOK 1
#define EOS_TOK 2

#define NBLK 64             // grid blocks (co-resident via cooperative launch)
#define NTHR 512            // threads per block (8 waves)
#define VC   786            // ceil(V_SZ / NBLK); last block vn = 739

// ---------------- workspace layout (float indices; f64 slots at even idx) ----
#define ST_A_F   0          // double[4480]: h1[10][128],c1[10][128],h2[10][64],c2,ctx
#define ST_B_F   8960
#define SD_H1    0
#define SD_C1    1280
#define SD_H2    2560
#define SD_C2    3200
#define SD_CTX   3840
#define META_A_F 17920      // SC double[10](@0), FIN i32[10](@20), PREV i32[10](@30), SEQ i32[10][31](@40)
#define META_B_F 18272
#define M_SC     0
#define M_FIN    20
#define M_PREV   30
#define M_SEQ    40
#define XS_F     19936      // double[10][128]: {h2[64], ctx[64]} per beam (phase A -> phase B)
#define LSEM_F   83136      // double[64][10]
#define LSES_F   88256      // double[64][10]
#define CANDV_F  93376      // float[64][10][10]
#define CANDI_F  118976     // int[64][10][10]
#define B10V_F   144576     // double[10][10] per-beam top10 values
#define B10F_F   144776     // int[10][10]   per-beam top10 flat indices
#define BAR_F    145408     // int[(NBLK+1)*32] custom grid barrier (128B-spaced slots)
#define BAR_BYTES ((NBLK + 1) * 32 * 4)

// ---------------- custom low-contention grid barrier ----------------
// Per-block arrival flags on separate 128B lines (plain release stores, no RMW),
// block 0 wave-parallel polls arrivals, single release flag, s_sleep backoff.
// Epochs are monotone; BAR region is zeroed by hipMemsetAsync before each launch.
__device__ __forceinline__ void gbar(int* bar, int blk, int tid, int e) {
  __syncthreads();
  __threadfence();   // release: make this block's writes device-visible
  if (tid == 0)
    __hip_atomic_store(&bar[blk * 32], e, __ATOMIC_RELEASE, __HIP_MEMORY_SCOPE_AGENT);
  if (blk == 0) {
    if (tid < NBLK) {
      while (__hip_atomic_load(&bar[tid * 32], __ATOMIC_RELAXED, __HIP_MEMORY_SCOPE_AGENT) < e)
        __builtin_amdgcn_s_sleep(2);
    }
    __syncthreads();
    if (tid == 0)
      __hip_atomic_store(&bar[NBLK * 32], e, __ATOMIC_RELEASE, __HIP_MEMORY_SCOPE_AGENT);
  } else {
    if (tid == 0) {
      while (__hip_atomic_load(&bar[NBLK * 32], __ATOMIC_RELAXED, __HIP_MEMORY_SCOPE_AGENT) < e)
        __builtin_amdgcn_s_sleep(2);
    }
  }
  __syncthreads();
  __threadfence();   // acquire: invalidate stale L1/L2 before reading others' writes
}

// ---------------- wave helpers ----------------
__device__ __forceinline__ void wave_merge_ms_d(double& m, double& s) {
  #pragma unroll
  for (int off = 32; off > 0; off >>= 1) {
    double om = __shfl_down(m, off, 64);
    double os = __shfl_down(s, off, 64);
    double nm = fmax(m, om);
    s = s * exp(m - nm) + os * exp(om - nm);
    m = nm;
  }
}
__device__ __forceinline__ void wave_argmax_f(float& v, int& i) {
  #pragma unroll
  for (int off = 32; off > 0; off >>= 1) {
    float ov = __shfl_down(v, off, 64);
    int   oi = __shfl_down(i, off, 64);
    if (ov > v || (ov == v && oi < i)) { v = ov; i = oi; }
  }
}

// merge 100 per-beam candidates (global B10V/B10F) -> global top-10 picks.
// Executed by wave 0 of a block. Order: (value desc, flat asc).
__device__ __forceinline__ void merge100(const float* ws, double* selv, int* self_, int lane) {
  const double* bv = (const double*)(ws + B10V_F);
  const int*    bf = (const int*)(ws + B10F_F);
  double av = (lane < 100) ? bv[lane] : -1e302;
  int    af = (lane < 100) ? bf[lane] : 0x7fffffff;
  const int c1 = lane + 64;
  double cv = (c1 < 100) ? bv[c1] : -1e302;
  int    cf = (c1 < 100) ? bf[c1] : 0x7fffffff;
  #pragma unroll
  for (int pick = 0; pick < 10; ++pick) {
    bool tb = (cv > av) || (cv == av && cf < af);
    double lv = tb ? cv : av;
    int    lf = tb ? cf : af;
    int    ls = tb ? c1 : lane;
    #pragma unroll
    for (int off = 32; off > 0; off >>= 1) {
      double ov = __shfl_down(lv, off, 64);
      int    of = __shfl_down(lf, off, 64);
      int    os = __shfl_down(ls, off, 64);
      if (ov > lv || (ov == lv && of < lf)) { lv = ov; lf = of; ls = os; }
    }
    ls = __shfl(ls, 0, 64);
    if (lane == 0) { selv[pick] = lv; self_[pick] = lf; }
    if (ls == lane) { av = -1e302; af = 0x7fffffff; }   // destructively exclude
    if (ls == c1)   { cv = -1e302; cf = 0x7fffffff; }
  }
}

// ---------------- the persistent cooperative kernel ----------------
__global__ __launch_bounds__(NTHR, 2) void beam_fused(
    float* __restrict__ ws, float* __restrict__ out,
    const float* __restrict__ enc_key, const float* __restrict__ enc_values,
    const float* __restrict__ maskp, const float* __restrict__ embedding,
    const float* __restrict__ W_ih1, const float* __restrict__ W_hh1,
    const float* __restrict__ b_ih1, const float* __restrict__ b_hh1,
    const float* __restrict__ W_ih2, const float* __restrict__ W_hh2,
    const float* __restrict__ b_ih2, const float* __restrict__ b_hh2,
    const float* __restrict__ Wq, const float* __restrict__ bq,
    const float* __restrict__ Wc, const float* __restrict__ bc)
{
  const int tid  = threadIdx.x;
  const int blk  = blockIdx.x;
  const int lane = tid & 63;
  const int wv   = tid >> 6;
  int* bar = (int*)(ws + BAR_F);
  int ep = 0;

  // ---- shared memory (union of all phases; ~76 KB, 1 block/CU) ----
  __shared__ double sh_e[T_SZ];        // energies -> attention weights
  __shared__ double sh_red[NTHR];      // block reductions
  __shared__ double sh_xin[192];
  __shared__ double sh_h1p[128];
  __shared__ double sh_g1[512];
  __shared__ double sh_h1n[128];
  __shared__ double sh_h2p[64];
  __shared__ double sh_gt2[256];
  __shared__ double sh_h2n[64];
  __shared__ double sh_qs[64];
  __shared__ double sh_xs[K_BEAM*128]; // phase B input
  __shared__ float  sh_lg[VC*K_BEAM];  // phase B logits (786*10 floats = 31.4 KB)
  __shared__ double sh_selv[10];       // global picks (values)
  __shared__ int    sh_self[10];       // global picks (flat)
  __shared__ double sh_wtv[80];        // SEL: per-wave top10
  __shared__ int    sh_wti[80];
  __shared__ double sh_base;
  __shared__ double sh_sc;
  __shared__ int    sh_pb, sh_tok;
  __shared__ int    sh_seqF[K_BEAM*SEQ_LEN];
  __shared__ int    sh_fpb[K_BEAM], sh_ftok[K_BEAM];

  // ---- init: blocks 0..9 init their own beam's state (block-local) ----
  if (blk < K_BEAM) {
    double* SA = (double*)(ws + ST_A_F);
    if (tid < 128) { SA[SD_H1 + blk*H1_SZ + tid] = 0.0; SA[SD_C1 + blk*H1_SZ + tid] = 0.0; }
    if (tid >= 128 && tid < 192) {
      int i2 = tid - 128;
      SA[SD_H2 + blk*H2_SZ + i2] = 0.0; SA[SD_C2 + blk*H2_SZ + i2] = 0.0;
      SA[SD_CTX + blk*Q_SZ + i2] = 0.0;
    }
    float* mA = ws + META_A_F;
    if (tid == 0) {
      ((double*)(mA + M_SC))[blk] = 0.0;
      ((int*)(mA + M_FIN))[blk] = 0;
      ((int*)(mA + M_PREV))[blk] = SOS_TOK;
    }
    if (tid < SEQ_LEN) ((int*)(mA + M_SEQ))[blk*SEQ_LEN + tid] = SOS_TOK;
  }

  for (int step = 0; step < MAXLEN; ++step) {
    // =================== PHASE A: blocks 0..9 (beam b = blk) ===================
    if (blk < K_BEAM) {
      const int b = blk;
      const int par = step & 1;
      const double* S = (const double*)(ws + (par == 0 ? ST_A_F : ST_B_F));
      double*       D = (double*)(ws + (par == 0 ? ST_B_F : ST_A_F));
      const float* msrc = ws + (par == 0 ? META_A_F : META_B_F);
      float*       mdst = ws + (par == 0 ? META_B_F : META_A_F);
      __syncthreads();

      // ---- decode pick for this beam ----
      if (step == 0) {
        if (tid == 0) {
          int tok = ((const int*)(msrc + M_PREV))[b];
          double sc = ((const double*)(msrc + M_SC))[b];
          int fin = ((const int*)(msrc + M_FIN))[b];
          sh_pb = b; sh_tok = tok; sh_sc = sc;
          ((double*)(mdst + M_SC))[b] = sc;
          ((int*)(mdst + M_FIN))[b] = fin;
          ((int*)(mdst + M_PREV))[b] = tok;
        }
      } else {
        if (wv == 0) merge100(ws, sh_selv, sh_self, lane);  // redundant in 10 blocks; saves a barrier
        __syncthreads();
        if (tid == 0) {
          int f = sh_self[b];
          int pb = f / V_SZ; int tok = f - pb*V_SZ;
          pb = min(max(pb, 0), K_BEAM - 1); tok = min(max(tok, 0), V_SZ - 1);
          double sc = sh_selv[b];
          int fin = ((const int*)(msrc + M_FIN))[pb] | (tok == EOS_TOK);
          sh_pb = pb; sh_tok = tok; sh_sc = sc;
          ((double*)(mdst + M_SC))[b] = sc;
          ((int*)(mdst + M_FIN))[b] = fin;
          ((int*)(mdst + M_PREV))[b] = tok;
        }
      }
      __syncthreads();
      const int pb = sh_pb, tok = sh_tok;

      // seq copy + input staging
      if (tid < SEQ_LEN) {
        int v = ((const int*)(msrc + M_SEQ))[pb*SEQ_LEN + tid];
        if (step > 0 && tid == step) v = tok;
        ((int*)(mdst + M_SEQ))[b*SEQ_LEN + tid] = v;
      }
      if (tid < 128)                     sh_xin[tid] = (double)embedding[(size_t)tok*E_SZ + tid];
      else if (tid < 192)                sh_xin[tid] = S[SD_CTX + pb*Q_SZ + (tid - 128)];
      if (tid >= 256 && tid < 384)       sh_h1p[tid - 256] = S[SD_H1 + pb*H1_SZ + (tid - 256)];
      __syncthreads();

      // ---- LSTM1 gates: 512 rows, 1 row/thread ----
      {
        const int r = tid;
        double acc = (double)b_ih1[r] + (double)b_hh1[r];
        const float4* wi = (const float4*)(W_ih1 + (size_t)r*192);
        #pragma unroll 8
        for (int j = 0; j < 48; ++j) {
          float4 w = wi[j];
          acc += (double)w.x*sh_xin[4*j]   + (double)w.y*sh_xin[4*j+1]
               + (double)w.z*sh_xin[4*j+2] + (double)w.w*sh_xin[4*j+3];
        }
        const float4* wh = (const float4*)(W_hh1 + (size_t)r*128);
        #pragma unroll 8
        for (int j = 0; j < 32; ++j) {
          float4 w = wh[j];
          acc += (double)w.x*sh_h1p[4*j]   + (double)w.y*sh_h1p[4*j+1]
               + (double)w.z*sh_h1p[4*j+2] + (double)w.w*sh_h1p[4*j+3];
        }
        sh_g1[r] = acc;
      }
      __syncthreads();
      // LSTM1 activation
      if (tid < 128) {
        double ig = 1.0/(1.0 + exp(-sh_g1[tid]));
        double fg = 1.0/(1.0 + exp(-sh_g1[128 + tid]));
        double gg = tanh(sh_g1[256 + tid]);
        double og = 1.0/(1.0 + exp(-sh_g1[384 + tid]));
        double c = fg * S[SD_C1 + pb*H1_SZ + tid] + ig*gg;
        double h = og * tanh(c);
        D[SD_C1 + b*H1_SZ + tid] = c; D[SD_H1 + b*H1_SZ + tid] = h;
        sh_h1n[tid] = h;
      }
      if (tid >= 128 && tid < 192) sh_h2p[tid - 128] = S[SD_H2 + pb*H2_SZ + (tid - 128)];
      __syncthreads();

      // ---- LSTM2 gates: 256 rows ----
      if (tid < 256) {
        const int r = tid;
        double acc = (double)b_ih2[r] + (double)b_hh2[r];
        const float4* wi2 = (const float4*)(W_ih2 + (size_t)r*128);
        #pragma unroll 8
        for (int j = 0; j < 32; ++j) {
          float4 w = wi2[j];
          acc += (double)w.x*sh_h1n[4*j]   + (double)w.y*sh_h1n[4*j+1]
               + (double)w.z*sh_h1n[4*j+2] + (double)w.w*sh_h1n[4*j+3];
        }
        const float4* wh2 = (const float4*)(W_hh2 + (size_t)r*64);
        #pragma unroll 8
        for (int j = 0; j < 16; ++j) {
          float4 w = wh2[j];
          acc += (double)w.x*sh_h2p[4*j]   + (double)w.y*sh_h2p[4*j+1]
               + (double)w.z*sh_h2p[4*j+2] + (double)w.w*sh_h2p[4*j+3];
        }
        sh_gt2[r] = acc;
      }
      __syncthreads();
      // LSTM2 activation + h2 out
      if (tid < 64) {
        double ig = 1.0/(1.0 + exp(-sh_gt2[tid]));
        double fg = 1.0/(1.0 + exp(-sh_gt2[64 + tid]));
        double gg = tanh(sh_gt2[128 + tid]);
        double og = 1.0/(1.0 + exp(-sh_gt2[192 + tid]));
        double c = fg * S[SD_C2 + pb*H2_SZ + tid] + ig*gg;
        double h = og * tanh(c);
        D[SD_C2 + b*H2_SZ + tid] = c; D[SD_H2 + b*H2_SZ + tid] = h;
        sh_h2n[tid] = h;
        ((double*)(ws + XS_F))[b*128 + tid] = h;
      }
      __syncthreads();
      // q
      if (tid < 64) {
        double acc = (double)bq[tid];
        const float4* wr = (const float4*)(Wq + (size_t)tid*64);
        #pragma unroll
        for (int j = 0; j < 16; ++j) {
          float4 w = wr[j];
          acc += (double)w.x*sh_h2n[4*j]   + (double)w.y*sh_h2n[4*j+1]
               + (double)w.z*sh_h2n[4*j+2] + (double)w.w*sh_h2n[4*j+3];
        }
        sh_qs[tid] = acc;
      }
      __syncthreads();

      // ---- attention: energies, softmax, masked renorm, ctx ----
      double lmax = -1e300;
      for (int t = tid; t < T_SZ; t += NTHR) {
        const float4* kr = (const float4*)(enc_key + (size_t)t*64);
        double e = 0.0;
        #pragma unroll
        for (int j = 0; j < 16; ++j) {
          float4 k2 = kr[j];
          e += (double)k2.x*sh_qs[4*j]   + (double)k2.y*sh_qs[4*j+1]
             + (double)k2.z*sh_qs[4*j+2] + (double)k2.w*sh_qs[4*j+3];
        }
        sh_e[t] = e;
        lmax = fmax(lmax, e);
      }
      sh_red[tid] = lmax; __syncthreads();
      for (int s2 = 256; s2 > 0; s2 >>= 1) { if (tid < s2) sh_red[tid] = fmax(sh_red[tid], sh_red[tid + s2]); __syncthreads(); }
      const double mx = sh_red[0]; __syncthreads();
      double lsum = 0.0;
      for (int t = tid; t < T_SZ; t += NTHR) lsum += exp(sh_e[t] - mx);
      sh_red[tid] = lsum; __syncthreads();
      for (int s2 = 256; s2 > 0; s2 >>= 1) { if (tid < s2) sh_red[tid] += sh_red[tid + s2]; __syncthreads(); }
      const double Ss = sh_red[0]; __syncthreads();
      double lms = 0.0;
      for (int t = tid; t < T_SZ; t += NTHR) {
        double w = (double)maskp[t] * (exp(sh_e[t] - mx) / Ss);
        sh_e[t] = w;
        lms += w;
      }
      sh_red[tid] = lms; __syncthreads();
      for (int s2 = 256; s2 > 0; s2 >>= 1) { if (tid < s2) sh_red[tid] += sh_red[tid + s2]; __syncthreads(); }
      const double ms = fmax(sh_red[0], 2e-30); __syncthreads();
      {
        const int v = tid & 63, g = tid >> 6;   // 8 groups of 64
        double acc = 0.0;
        for (int k = 0; k < 256; ++k) {
          int t = g + 8*k;
          acc += sh_e[t] * (double)enc_values[(size_t)t*64 + v];
        }
        sh_red[tid] = acc;
      }
      __syncthreads();
      if (tid < 64) {
        double cv = 0.0;
        #pragma unroll
        for (int g = 0; g < 8; ++g) cv += sh_red[g*64 + tid];
        cv /= ms;
        D[SD_CTX + b*Q_SZ + tid] = cv;
        ((double*)(ws + XS_F))[b*128 + 64 + tid] = cv;
      }
    }
    gbar(bar, blk, tid, ++ep);

    // =================== PHASE B: all 64 blocks — logits, LSE, block top-10 ===================
    {
      const int v0 = blk * VC;
      const int vn = min(VC, V_SZ - v0);
      __syncthreads();
      for (int i2 = tid; i2 < K_BEAM*128; i2 += NTHR) sh_xs[i2] = ((const double*)(ws + XS_F))[i2];
      __syncthreads();
      for (int vl = tid; vl < vn; vl += NTHR) {
        const float4* wr = (const float4*)(Wc + (size_t)(v0 + vl)*128);
        double acc[K_BEAM];
        #pragma unroll
        for (int b2 = 0; b2 < K_BEAM; ++b2) acc[b2] = 0.0;
        for (int j = 0; j < 32; ++j) {
          float4 w = wr[j];
          double w0 = (double)w.x, w1 = (double)w.y, w2 = (double)w.z, w3 = (double)w.w;
          #pragma unroll
          for (int b2 = 0; b2 < K_BEAM; ++b2) acc[b2] += w0 * sh_xs[b2*128 + 4*j];
          #pragma unroll
          for (int b2 = 0; b2 < K_BEAM; ++b2) acc[b2] += w1 * sh_xs[b2*128 + 4*j + 1];
          #pragma unroll
          for (int b2 = 0; b2 < K_BEAM; ++b2) acc[b2] += w2 * sh_xs[b2*128 + 4*j + 2];
          #pragma unroll
          for (int b2 = 0; b2 < K_BEAM; ++b2) acc[b2] += w3 * sh_xs[b2*128 + 4*j + 3];
        }
        double bcv = (double)bc[v0 + vl];
        #pragma unroll
        for (int b2 = 0; b2 < K_BEAM; ++b2) sh_lg[vl*K_BEAM + b2] = (float)(acc[b2] + bcv);
      }
      __syncthreads();

      double* lse_m = (double*)(ws + LSEM_F);
      double* lse_s = (double*)(ws + LSES_F);
      float*  cvv   = ws + CANDV_F;
      int*    cii   = (int*)(ws + CANDI_F);
      for (int b2 = wv; b2 < K_BEAM; b2 += 8) {
        double m = -1e300, s = 0.0;
        for (int vl = lane; vl < vn; vl += 64) {
          double val = (double)sh_lg[vl*K_BEAM + b2];
          double nm = fmax(m, val);
          s = s*exp(m - nm) + exp(val - nm); m = nm;
        }
        wave_merge_ms_d(m, s);
        if (lane == 0) { lse_m[blk*K_BEAM + b2] = m; lse_s[blk*K_BEAM + b2] = s; }
        // top-10 with destructive exclusion (cells of beam b2 owned exclusively by this wave)
        #pragma unroll
        for (int pick = 0; pick < 10; ++pick) {
          float bv = -3e38f; int bi = 0x7ffffff0;
          for (int vl = lane; vl < vn; vl += 64) {
            float val = sh_lg[vl*K_BEAM + b2];
            if (val > bv || (val == bv && vl < bi)) { bv = val; bi = vl; }
          }
          wave_argmax_f(bv, bi);
          bv = __shfl(bv, 0, 64); bi = __shfl(bi, 0, 64);
          int wi = min(max(bi, 0), vn - 1);
          if (lane == 0) {
            cvv[(blk*K_BEAM + b2)*10 + pick] = bv;
            cii[(blk*K_BEAM + b2)*10 + pick] = v0 + wi;
          }
          if (bi >= 0 && bi < vn && (bi & 63) == lane) sh_lg[bi*K_BEAM + b2] = -3e38f;
        }
      }
    }
    gbar(bar, blk, tid, ++ep);

    // =================== PHASE SEL: blocks 0..9, beam j = blk — per-beam top-10 of 640 ===================
    if (blk < K_BEAM) {
      const int j = blk;
      const int par = step & 1;
      const float* mcur = ws + (par == 0 ? META_B_F : META_A_F);   // META written this step
      const double scj = ((const double*)(mcur + M_SC))[j];
      const int finj   = ((const int*)(mcur + M_FIN))[j];
      const bool masked = finj || (step == 0 && j > 0);

      if (wv == 0) {
        double m = -1e300, s = 0.0;
        for (int c = lane; c < NBLK; c += 64) {
          double mc  = ((const double*)(ws + LSEM_F))[c*K_BEAM + j];
          double sc2 = ((const double*)(ws + LSES_F))[c*K_BEAM + j];
          double nm = fmax(m, mc);
          s = s*exp(m - nm) + sc2*exp(mc - nm); m = nm;
        }
        wave_merge_ms_d(m, s);
        if (lane == 0) sh_base = scj - (m + log(s));
      }
      __syncthreads();
      const double base = sh_base;

      // each wave: local top-10 over its 80 candidates (640 total = NBLK*10)
      float rv[2]; int ri[2];
      #pragma unroll
      for (int k = 0; k < 2; ++k) {
        int cc = 64*k + lane;
        if (cc < 80) {
          int c = wv*80 + cc;
          int blkc = c / 10, p = c - blkc*10;
          int idx = (blkc*K_BEAM + j)*10 + p;
          rv[k] = (ws + CANDV_F)[idx];
          ri[k] = ((const int*)(ws + CANDI_F))[idx];
        } else { rv[k] = -3e38f; ri[k] = 0x7ffffff0; }
      }
      #pragma unroll
      for (int pick = 0; pick < 10; ++pick) {
        double lv = -1e301; int li = 0x7ffffff0;
        if (!masked) {
          #pragma unroll
          for (int k = 0; k < 2; ++k) {
            double val = base + (double)rv[k];
            int v = ri[k];
            if (val > lv || (val == lv && v < li)) { lv = val; li = v; }
          }
        }
        #pragma unroll
        for (int off = 32; off > 0; off >>= 1) {
          double ov = __shfl_down(lv, off, 64);
          int    oi = __shfl_down(li, off, 64);
          if (ov > lv || (ov == lv && oi < li)) { lv = ov; li = oi; }
        }
        lv = __shfl(lv, 0, 64); li = __shfl(li, 0, 64);
        if (!masked) {
          #pragma unroll
          for (int k = 0; k < 2; ++k) if (ri[k] == li) rv[k] = -3e38f;  // destructive exclude
        }
        if (lane == 0) { sh_wtv[wv*10 + pick] = lv; sh_wti[wv*10 + pick] = li; }
      }
      __syncthreads();

      // wave 0: merge 80 -> 10, write global B10
      if (wv == 0) {
        double av = (lane < 80) ? sh_wtv[lane] : -1e305;
        int    ai = (lane < 80) ? sh_wti[lane] : 0x7fffffff;
        const int c1 = lane + 64;
        double bv2 = (c1 < 80) ? sh_wtv[c1] : -1e305;
        int    bi2 = (c1 < 80) ? sh_wti[c1] : 0x7fffffff;
        #pragma unroll
        for (int pick = 0; pick < 10; ++pick) {
          bool tb = (bv2 > av) || (bv2 == av && bi2 < ai);
          double lv = tb ? bv2 : av;
          int    li = tb ? bi2 : ai;
          int    ls = tb ? c1  : lane;
          #pragma unroll
          for (int off = 32; off > 0; off >>= 1) {
            double ov = __shfl_down(lv, off, 64);
            int    oi = __shfl_down(li, off, 64);
            int    os = __shfl_down(ls, off, 64);
            if (ov > lv || (ov == lv && oi < li)) { lv = ov; li = oi; ls = os; }
          }
          ls = __shfl(ls, 0, 64);
          if (ls == lane) { av  = -1e305; ai  = 0x7fffffff; }
          if (ls == c1)   { bv2 = -1e305; bi2 = 0x7fffffff; }
          if (lane == 0) {
            double outv; int outf;
            if (finj) {
              outv = (pick == 0) ? scj : -1e301;
              outf = (pick == 0) ? (j*V_SZ + EOS_TOK) : 0x7ffffff0;
            } else if (step == 0 && j > 0) {
              outv = -1e301; outf = 0x7ffffff0;
            } else {
              outv = lv;
              outf = j*V_SZ + min(max(li, 0), V_SZ - 1);
            }
            ((double*)(ws + B10V_F))[j*10 + pick] = outv;
            ((int*)(ws + B10F_F))[j*10 + pick] = outf;
          }
        }
      }
    }
    gbar(bar, blk, tid, ++ep);
  } // step loop

  // =================== FINAL: block 0 — last selection + gather + output ===================
  if (blk == 0) {
    __syncthreads();
    if (wv == 0) merge100(ws, sh_selv, sh_self, lane);
    __syncthreads();
    const float* mA = ws + META_A_F;              // dst of step 29 (odd -> A)
    const int* seqA = (const int*)(mA + M_SEQ);
    if (tid < K_BEAM) {
      int f = sh_self[tid];
      int pb = f / V_SZ, tk2 = f - pb*V_SZ;
      sh_fpb[tid]  = min(max(pb, 0), K_BEAM - 1);
      sh_ftok[tid] = min(max(tk2, 0), V_SZ - 1);
    }
    __syncthreads();
    for (int t = tid; t < K_BEAM*SEQ_LEN; t += NTHR) {
      int j2 = t / SEQ_LEN, p = t - j2*SEQ_LEN;
      sh_seqF[t] = (p == MAXLEN) ? sh_ftok[j2] : seqA[sh_fpb[j2]*SEQ_LEN + p];
    }
    __syncthreads();
    if (tid < K_BEAM) {
      int first = -1;
      for (int p = 1; p <= MAXLEN; ++p)
        if (sh_seqF[tid*SEQ_LEN + p] == EOS_TOK) { first = p - 1; break; }
      double len = (first >= 0) ? (double)(first + 2) : (double)(MAXLEN + 2);
      double scv = sh_selv[tid];
      out[K_BEAM*SEQ_LEN + tid] = (float)scv;
      out[K_BEAM*SEQ_LEN + K_BEAM + tid] = (float)(scv / pow(len, 1.2));
    }
    for (int t = tid; t < K_BEAM*SEQ_LEN; t += NTHR) out[t] = (float)sh_seqF[t];
  }
}

// ---------------- host ----------------
extern "C" void kernel_launch(void* const* d_in, const int* in_sizes, int n_in,
                              void* d_out, int out_size, void* d_ws, size_t ws_size,
                              hipStream_t stream) {
  (void)in_sizes; (void)n_in; (void)out_size; (void)ws_size;
  const float* enc_key    = (const float*)d_in[0];
  const float* enc_values = (const float*)d_in[1];
  const float* maskp      = (const float*)d_in[2];
  const float* embedding  = (const float*)d_in[3];
  const float* W_ih1      = (const float*)d_in[4];
  const float* W_hh1      = (const float*)d_in[5];
  const float* b_ih1      = (const float*)d_in[6];
  const float* b_hh1      = (const float*)d_in[7];
  const float* W_ih2      = (const float*)d_in[8];
  const float* W_hh2      = (const float*)d_in[9];
  const float* b_ih2      = (const float*)d_in[10];
  const float* b_hh2      = (const float*)d_in[11];
  const float* Wq         = (const float*)d_in[12];
  const float* bq         = (const float*)d_in[13];
  const float* Wc         = (const float*)d_in[14];
  const float* bc         = (const float*)d_in[15];
  float* ws  = (float*)d_ws;
  float* out = (float*)d_out;

  // zero the barrier epoch region (graph-capturable; re-runs on each graph replay)
  hipMemsetAsync((char*)d_ws + (size_t)BAR_F * 4, 0, BAR_BYTES, stream);

  void* args[] = { (void*)&ws, (void*)&out,
                   (void*)&enc_key, (void*)&enc_values, (void*)&maskp, (void*)&embedding,
                   (void*)&W_ih1, (void*)&W_hh1, (void*)&b_ih1, (void*)&b_hh1,
                   (void*)&W_ih2, (void*)&W_hh2, (void*)&b_ih2, (void*)&b_hh2,
                   (void*)&Wq, (void*)&bq, (void*)&Wc, (void*)&bc };
  hipLaunchCooperativeKernel((const void*)beam_fused, dim3(NBLK), dim3(NTHR), args, 0, stream);
}

// Round 3
// 6034.459 us; speedup vs baseline: 1.9001x; 1.3362x over previous
//
#include <hip/hip_runtime.h>
#include <math.h>

// ---------------- problem constants ----------------
#define K_BEAM  10
#define V_SZ    50257
#define E_SZ    128
#define H1_SZ   128
#define H2_SZ   64
#define Q_SZ    64
#define T_SZ    2048
#define MAXLEN  30
#define SEQ_LEN 31
#define SOS_TOK 1
#define EOS_TOK 2

#define NBLK 256            // grid blocks (1/CU, co-resident via cooperative launch)
#define NTHR 512            // threads per block (8 waves)
#define VC   197            // ceil(V_SZ / NBLK); last block vn = 22

// ---------------- workspace layout (float indices; f64 slots at even idx) ----
#define ST_A_F   0          // double[4480]: h1[10][128],c1[10][128],h2[10][64],c2,ctx
#define ST_B_F   8960
#define SD_H1    0
#define SD_C1    1280
#define SD_H2    2560
#define SD_C2    3200
#define SD_CTX   3840
#define META_A_F 17920      // SC double[10](@0), FIN i32[10](@20), PREV i32[10](@30), SEQ i32[10][31](@40)
#define META_B_F 18272
#define M_SC     0
#define M_FIN    20
#define M_PREV   30
#define M_SEQ    40
#define XS_F     19936      // double[10][128]: {h2[64], ctx[64]} per beam (phase A -> phase B)
#define LSEM_F   83136      // double[256][10]
#define LSES_F   88256      // double[256][10]
#define CANDV_F  93376      // float[256][10][10]
#define CANDI_F  118976     // int[256][10][10]
#define B10V_F   144576     // double[10][10] per-beam top10 values
#define B10F_F   144776     // int[10][10]   per-beam top10 flat indices
#define BAR_F    145408     // int[2*NBLK*32]: arrival[blk*32], release[(NBLK+blk)*32]
#define BAR_BYTES (2 * NBLK * 32 * 4)

// ---------------- agent-scope atomic access (bypasses non-coherent L2) -------
// All cross-block payload goes through these; read-only inputs stay plain
// cached loads so L2 keeps Wc/enc/weights hot across steps (no fences, no inv).
__device__ __forceinline__ double ldg_d(const double* p) {
  return __hip_atomic_load((double*)p, __ATOMIC_RELAXED, __HIP_MEMORY_SCOPE_AGENT);
}
__device__ __forceinline__ void stg_d(double* p, double v) {
  __hip_atomic_store(p, v, __ATOMIC_RELAXED, __HIP_MEMORY_SCOPE_AGENT);
}
__device__ __forceinline__ float ldg_f(const float* p) {
  return __hip_atomic_load((float*)p, __ATOMIC_RELAXED, __HIP_MEMORY_SCOPE_AGENT);
}
__device__ __forceinline__ void stg_f(float* p, float v) {
  __hip_atomic_store(p, v, __ATOMIC_RELAXED, __HIP_MEMORY_SCOPE_AGENT);
}
__device__ __forceinline__ int ldg_i(const int* p) {
  return __hip_atomic_load((int*)p, __ATOMIC_RELAXED, __HIP_MEMORY_SCOPE_AGENT);
}
__device__ __forceinline__ void stg_i(int* p, int v) {
  __hip_atomic_store(p, v, __ATOMIC_RELAXED, __HIP_MEMORY_SCOPE_AGENT);
}

// ---------------- fence-free grid barrier ----------------
// Payload stores are sc-atomics: vmcnt(0) drain (explicit + inside syncthreads)
// means they are performed at the coherence point before the arrival flag.
// Per-block release slots: no hot cacheline. Epochs monotone; BAR zeroed by
// hipMemsetAsync before launch (graph-replay safe).
__device__ __forceinline__ void gbar(int* bar, int blk, int tid, int e) {
  asm volatile("s_waitcnt vmcnt(0)" ::: "memory");
  __syncthreads();
  if (blk == 0) {
    if (tid > 0 && tid < NBLK) {
      while (__hip_atomic_load(&bar[tid * 32], __ATOMIC_RELAXED, __HIP_MEMORY_SCOPE_AGENT) < e)
        __builtin_amdgcn_s_sleep(1);
    }
    __syncthreads();
    if (tid < NBLK)
      __hip_atomic_store(&bar[(NBLK + tid) * 32], e, __ATOMIC_RELAXED, __HIP_MEMORY_SCOPE_AGENT);
  } else {
    if (tid == 0) {
      __hip_atomic_store(&bar[blk * 32], e, __ATOMIC_RELAXED, __HIP_MEMORY_SCOPE_AGENT);
      while (__hip_atomic_load(&bar[(NBLK + blk) * 32], __ATOMIC_RELAXED, __HIP_MEMORY_SCOPE_AGENT) < e)
        __builtin_amdgcn_s_sleep(1);
    }
    __syncthreads();
  }
  asm volatile("" ::: "memory");
}

// ---------------- wave helpers ----------------
__device__ __forceinline__ void wave_merge_ms_d(double& m, double& s) {
  #pragma unroll
  for (int off = 32; off > 0; off >>= 1) {
    double om = __shfl_down(m, off, 64);
    double os = __shfl_down(s, off, 64);
    double nm = fmax(m, om);
    s = s * exp(m - nm) + os * exp(om - nm);
    m = nm;
  }
}
__device__ __forceinline__ void wave_argmax_f(float& v, int& i) {
  #pragma unroll
  for (int off = 32; off > 0; off >>= 1) {
    float ov = __shfl_down(v, off, 64);
    int   oi = __shfl_down(i, off, 64);
    if (ov > v || (ov == v && oi < i)) { v = ov; i = oi; }
  }
}

// merge 100 per-beam candidates (global B10V/B10F) -> global top-10 picks.
// Executed by wave 0 of a block. Order: (value desc, flat asc).
__device__ __forceinline__ void merge100(const float* ws, double* selv, int* self_, int lane) {
  const double* bv = (const double*)(ws + B10V_F);
  const int*    bf = (const int*)(ws + B10F_F);
  double av = (lane < 100) ? ldg_d(&bv[lane]) : -1e302;
  int    af = (lane < 100) ? ldg_i(&bf[lane]) : 0x7fffffff;
  const int c1 = lane + 64;
  double cv = (c1 < 100) ? ldg_d(&bv[c1]) : -1e302;
  int    cf = (c1 < 100) ? ldg_i(&bf[c1]) : 0x7fffffff;
  #pragma unroll
  for (int pick = 0; pick < 10; ++pick) {
    bool tb = (cv > av) || (cv == av && cf < af);
    double lv = tb ? cv : av;
    int    lf = tb ? cf : af;
    int    ls = tb ? c1 : lane;
    #pragma unroll
    for (int off = 32; off > 0; off >>= 1) {
      double ov = __shfl_down(lv, off, 64);
      int    of = __shfl_down(lf, off, 64);
      int    os = __shfl_down(ls, off, 64);
      if (ov > lv || (ov == lv && of < lf)) { lv = ov; lf = of; ls = os; }
    }
    ls = __shfl(ls, 0, 64);
    if (lane == 0) { selv[pick] = lv; self_[pick] = lf; }
    if (ls == lane) { av = -1e302; af = 0x7fffffff; }   // destructively exclude
    if (ls == c1)   { cv = -1e302; cf = 0x7fffffff; }
  }
}

// ---------------- the persistent cooperative kernel ----------------
__global__ __launch_bounds__(NTHR, 2) void beam_fused(
    float* __restrict__ ws, float* __restrict__ out,
    const float* __restrict__ enc_key, const float* __restrict__ enc_values,
    const float* __restrict__ maskp, const float* __restrict__ embedding,
    const float* __restrict__ W_ih1, const float* __restrict__ W_hh1,
    const float* __restrict__ b_ih1, const float* __restrict__ b_hh1,
    const float* __restrict__ W_ih2, const float* __restrict__ W_hh2,
    const float* __restrict__ b_ih2, const float* __restrict__ b_hh2,
    const float* __restrict__ Wq, const float* __restrict__ bq,
    const float* __restrict__ Wc, const float* __restrict__ bc)
{
  const int tid  = threadIdx.x;
  const int blk  = blockIdx.x;
  const int lane = tid & 63;
  const int wv   = tid >> 6;
  int* bar = (int*)(ws + BAR_F);
  int ep = 0;

  // ---- shared memory (union of all phases; ~52 KB, 1 block/CU) ----
  __shared__ double sh_e[T_SZ];        // energies -> attention weights
  __shared__ double sh_red[NTHR];      // block reductions
  __shared__ double sh_xin[192];
  __shared__ double sh_h1p[128];
  __shared__ double sh_g1[512];
  __shared__ double sh_h1n[128];
  __shared__ double sh_h2p[64];
  __shared__ double sh_gt2[256];
  __shared__ double sh_h2n[64];
  __shared__ double sh_qs[64];
  __shared__ double sh_xs[K_BEAM*128]; // phase B input
  __shared__ float  sh_lg[VC*K_BEAM];  // phase B logits (197*10 floats)
  __shared__ double sh_selv[10];       // global picks (values)
  __shared__ int    sh_self[10];       // global picks (flat)
  __shared__ double sh_wtv[80];        // SEL: per-wave top10
  __shared__ int    sh_wti[80];
  __shared__ double sh_base;
  __shared__ int    sh_pb, sh_tok;
  __shared__ int    sh_seqF[K_BEAM*SEQ_LEN];
  __shared__ int    sh_fpb[K_BEAM], sh_ftok[K_BEAM];

  // ---- init: blocks 0..9 init their own beam's state (block-local) ----
  if (blk < K_BEAM) {
    double* SA = (double*)(ws + ST_A_F);
    if (tid < 128) { stg_d(&SA[SD_H1 + blk*H1_SZ + tid], 0.0); stg_d(&SA[SD_C1 + blk*H1_SZ + tid], 0.0); }
    if (tid >= 128 && tid < 192) {
      int i2 = tid - 128;
      stg_d(&SA[SD_H2 + blk*H2_SZ + i2], 0.0); stg_d(&SA[SD_C2 + blk*H2_SZ + i2], 0.0);
      stg_d(&SA[SD_CTX + blk*Q_SZ + i2], 0.0);
    }
    float* mA = ws + META_A_F;
    if (tid == 0) {
      stg_d(&((double*)(mA + M_SC))[blk], 0.0);
      stg_i(&((int*)(mA + M_FIN))[blk], 0);
      stg_i(&((int*)(mA + M_PREV))[blk], SOS_TOK);
    }
    if (tid < SEQ_LEN) stg_i(&((int*)(mA + M_SEQ))[blk*SEQ_LEN + tid], SOS_TOK);
  }

  for (int step = 0; step < MAXLEN; ++step) {
    // =================== PHASE A: blocks 0..9 (beam b = blk) ===================
    if (blk < K_BEAM) {
      const int b = blk;
      const int par = step & 1;
      const double* S = (const double*)(ws + (par == 0 ? ST_A_F : ST_B_F));
      double*       D = (double*)(ws + (par == 0 ? ST_B_F : ST_A_F));
      const float* msrc = ws + (par == 0 ? META_A_F : META_B_F);
      float*       mdst = ws + (par == 0 ? META_B_F : META_A_F);
      __syncthreads();

      // ---- decode pick for this beam ----
      if (step == 0) {
        if (tid == 0) {
          int tok = ldg_i(&((const int*)(msrc + M_PREV))[b]);
          double sc = ldg_d(&((const double*)(msrc + M_SC))[b]);
          int fin = ldg_i(&((const int*)(msrc + M_FIN))[b]);
          sh_pb = b; sh_tok = tok;
          stg_d(&((double*)(mdst + M_SC))[b], sc);
          stg_i(&((int*)(mdst + M_FIN))[b], fin);
          stg_i(&((int*)(mdst + M_PREV))[b], tok);
        }
      } else {
        if (wv == 0) merge100(ws, sh_selv, sh_self, lane);  // redundant in 10 blocks; saves a barrier
        __syncthreads();
        if (tid == 0) {
          int f = sh_self[b];
          int pb = f / V_SZ; int tok = f - pb*V_SZ;
          pb = min(max(pb, 0), K_BEAM - 1); tok = min(max(tok, 0), V_SZ - 1);
          double sc = sh_selv[b];
          int fin = ldg_i(&((const int*)(msrc + M_FIN))[pb]) | (tok == EOS_TOK);
          sh_pb = pb; sh_tok = tok;
          stg_d(&((double*)(mdst + M_SC))[b], sc);
          stg_i(&((int*)(mdst + M_FIN))[b], fin);
          stg_i(&((int*)(mdst + M_PREV))[b], tok);
        }
      }
      __syncthreads();
      const int pb = sh_pb, tok = sh_tok;

      // seq copy + input staging
      if (tid < SEQ_LEN) {
        int v = ldg_i(&((const int*)(msrc + M_SEQ))[pb*SEQ_LEN + tid]);
        if (step > 0 && tid == step) v = tok;
        stg_i(&((int*)(mdst + M_SEQ))[b*SEQ_LEN + tid], v);
      }
      if (tid < 128)                     sh_xin[tid] = (double)embedding[(size_t)tok*E_SZ + tid];
      else if (tid < 192)                sh_xin[tid] = ldg_d(&S[SD_CTX + pb*Q_SZ + (tid - 128)]);
      if (tid >= 256 && tid < 384)       sh_h1p[tid - 256] = ldg_d(&S[SD_H1 + pb*H1_SZ + (tid - 256)]);
      __syncthreads();

      // ---- LSTM1 gates: 512 rows, 1 row/thread ----
      {
        const int r = tid;
        double acc = (double)b_ih1[r] + (double)b_hh1[r];
        const float4* wi = (const float4*)(W_ih1 + (size_t)r*192);
        #pragma unroll 8
        for (int j = 0; j < 48; ++j) {
          float4 w = wi[j];
          acc += (double)w.x*sh_xin[4*j]   + (double)w.y*sh_xin[4*j+1]
               + (double)w.z*sh_xin[4*j+2] + (double)w.w*sh_xin[4*j+3];
        }
        const float4* wh = (const float4*)(W_hh1 + (size_t)r*128);
        #pragma unroll 8
        for (int j = 0; j < 32; ++j) {
          float4 w = wh[j];
          acc += (double)w.x*sh_h1p[4*j]   + (double)w.y*sh_h1p[4*j+1]
               + (double)w.z*sh_h1p[4*j+2] + (double)w.w*sh_h1p[4*j+3];
        }
        sh_g1[r] = acc;
      }
      __syncthreads();
      // LSTM1 activation
      if (tid < 128) {
        double ig = 1.0/(1.0 + exp(-sh_g1[tid]));
        double fg = 1.0/(1.0 + exp(-sh_g1[128 + tid]));
        double gg = tanh(sh_g1[256 + tid]);
        double og = 1.0/(1.0 + exp(-sh_g1[384 + tid]));
        double c = fg * ldg_d(&S[SD_C1 + pb*H1_SZ + tid]) + ig*gg;
        double h = og * tanh(c);
        stg_d(&D[SD_C1 + b*H1_SZ + tid], c); stg_d(&D[SD_H1 + b*H1_SZ + tid], h);
        sh_h1n[tid] = h;
      }
      if (tid >= 128 && tid < 192) sh_h2p[tid - 128] = ldg_d(&S[SD_H2 + pb*H2_SZ + (tid - 128)]);
      __syncthreads();

      // ---- LSTM2 gates: 256 rows ----
      if (tid < 256) {
        const int r = tid;
        double acc = (double)b_ih2[r] + (double)b_hh2[r];
        const float4* wi2 = (const float4*)(W_ih2 + (size_t)r*128);
        #pragma unroll 8
        for (int j = 0; j < 32; ++j) {
          float4 w = wi2[j];
          acc += (double)w.x*sh_h1n[4*j]   + (double)w.y*sh_h1n[4*j+1]
               + (double)w.z*sh_h1n[4*j+2] + (double)w.w*sh_h1n[4*j+3];
        }
        const float4* wh2 = (const float4*)(W_hh2 + (size_t)r*64);
        #pragma unroll 8
        for (int j = 0; j < 16; ++j) {
          float4 w = wh2[j];
          acc += (double)w.x*sh_h2p[4*j]   + (double)w.y*sh_h2p[4*j+1]
               + (double)w.z*sh_h2p[4*j+2] + (double)w.w*sh_h2p[4*j+3];
        }
        sh_gt2[r] = acc;
      }
      __syncthreads();
      // LSTM2 activation + h2 out
      if (tid < 64) {
        double ig = 1.0/(1.0 + exp(-sh_gt2[tid]));
        double fg = 1.0/(1.0 + exp(-sh_gt2[64 + tid]));
        double gg = tanh(sh_gt2[128 + tid]);
        double og = 1.0/(1.0 + exp(-sh_gt2[192 + tid]));
        double c = fg * ldg_d(&S[SD_C2 + pb*H2_SZ + tid]) + ig*gg;
        double h = og * tanh(c);
        stg_d(&D[SD_C2 + b*H2_SZ + tid], c); stg_d(&D[SD_H2 + b*H2_SZ + tid], h);
        sh_h2n[tid] = h;
        stg_d(&((double*)(ws + XS_F))[b*128 + tid], h);
      }
      __syncthreads();
      // q
      if (tid < 64) {
        double acc = (double)bq[tid];
        const float4* wr = (const float4*)(Wq + (size_t)tid*64);
        #pragma unroll
        for (int j = 0; j < 16; ++j) {
          float4 w = wr[j];
          acc += (double)w.x*sh_h2n[4*j]   + (double)w.y*sh_h2n[4*j+1]
               + (double)w.z*sh_h2n[4*j+2] + (double)w.w*sh_h2n[4*j+3];
        }
        sh_qs[tid] = acc;
      }
      __syncthreads();

      // ---- attention: energies, softmax, masked renorm, ctx ----
      double lmax = -1e300;
      for (int t = tid; t < T_SZ; t += NTHR) {
        const float4* kr = (const float4*)(enc_key + (size_t)t*64);
        double e = 0.0;
        #pragma unroll
        for (int j = 0; j < 16; ++j) {
          float4 k2 = kr[j];
          e += (double)k2.x*sh_qs[4*j]   + (double)k2.y*sh_qs[4*j+1]
             + (double)k2.z*sh_qs[4*j+2] + (double)k2.w*sh_qs[4*j+3];
        }
        sh_e[t] = e;
        lmax = fmax(lmax, e);
      }
      sh_red[tid] = lmax; __syncthreads();
      for (int s2 = 256; s2 > 0; s2 >>= 1) { if (tid < s2) sh_red[tid] = fmax(sh_red[tid], sh_red[tid + s2]); __syncthreads(); }
      const double mx = sh_red[0]; __syncthreads();
      double lsum = 0.0;
      for (int t = tid; t < T_SZ; t += NTHR) lsum += exp(sh_e[t] - mx);
      sh_red[tid] = lsum; __syncthreads();
      for (int s2 = 256; s2 > 0; s2 >>= 1) { if (tid < s2) sh_red[tid] += sh_red[tid + s2]; __syncthreads(); }
      const double Ss = sh_red[0]; __syncthreads();
      double lms = 0.0;
      for (int t = tid; t < T_SZ; t += NTHR) {
        double w = (double)maskp[t] * (exp(sh_e[t] - mx) / Ss);
        sh_e[t] = w;
        lms += w;
      }
      sh_red[tid] = lms; __syncthreads();
      for (int s2 = 256; s2 > 0; s2 >>= 1) { if (tid < s2) sh_red[tid] += sh_red[tid + s2]; __syncthreads(); }
      const double ms = fmax(sh_red[0], 2e-30); __syncthreads();
      {
        const int v = tid & 63, g = tid >> 6;   // 8 groups of 64
        double acc = 0.0;
        for (int k = 0; k < 256; ++k) {
          int t = g + 8*k;
          acc += sh_e[t] * (double)enc_values[(size_t)t*64 + v];
        }
        sh_red[tid] = acc;
      }
      __syncthreads();
      if (tid < 64) {
        double cv = 0.0;
        #pragma unroll
        for (int g = 0; g < 8; ++g) cv += sh_red[g*64 + tid];
        cv /= ms;
        stg_d(&D[SD_CTX + b*Q_SZ + tid], cv);
        stg_d(&((double*)(ws + XS_F))[b*128 + 64 + tid], cv);
      }
    }
    gbar(bar, blk, tid, ++ep);

    // =================== PHASE B: all 256 blocks — logits, LSE, block top-10 ===================
    {
      const int v0 = blk * VC;
      const int vn = min(VC, V_SZ - v0);
      __syncthreads();
      for (int i2 = tid; i2 < K_BEAM*128; i2 += NTHR) sh_xs[i2] = ldg_d(&((const double*)(ws + XS_F))[i2]);
      __syncthreads();
      if (tid < vn) {
        const int vl = tid;
        const float4* wr = (const float4*)(Wc + (size_t)(v0 + vl)*128);
        double acc[K_BEAM];
        #pragma unroll
        for (int b2 = 0; b2 < K_BEAM; ++b2) acc[b2] = 0.0;
        for (int j = 0; j < 32; ++j) {
          float4 w = wr[j];
          double w0 = (double)w.x, w1 = (double)w.y, w2 = (double)w.z, w3 = (double)w.w;
          #pragma unroll
          for (int b2 = 0; b2 < K_BEAM; ++b2) acc[b2] += w0 * sh_xs[b2*128 + 4*j];
          #pragma unroll
          for (int b2 = 0; b2 < K_BEAM; ++b2) acc[b2] += w1 * sh_xs[b2*128 + 4*j + 1];
          #pragma unroll
          for (int b2 = 0; b2 < K_BEAM; ++b2) acc[b2] += w2 * sh_xs[b2*128 + 4*j + 2];
          #pragma unroll
          for (int b2 = 0; b2 < K_BEAM; ++b2) acc[b2] += w3 * sh_xs[b2*128 + 4*j + 3];
        }
        double bcv = (double)bc[v0 + vl];
        #pragma unroll
        for (int b2 = 0; b2 < K_BEAM; ++b2) sh_lg[vl*K_BEAM + b2] = (float)(acc[b2] + bcv);
      }
      __syncthreads();

      double* lse_m = (double*)(ws + LSEM_F);
      double* lse_s = (double*)(ws + LSES_F);
      float*  cvv   = ws + CANDV_F;
      int*    cii   = (int*)(ws + CANDI_F);
      for (int b2 = wv; b2 < K_BEAM; b2 += 8) {
        double m = -1e300, s = 0.0;
        for (int vl = lane; vl < vn; vl += 64) {
          double val = (double)sh_lg[vl*K_BEAM + b2];
          double nm = fmax(m, val);
          s = s*exp(m - nm) + exp(val - nm); m = nm;
        }
        wave_merge_ms_d(m, s);
        if (lane == 0) { stg_d(&lse_m[blk*K_BEAM + b2], m); stg_d(&lse_s[blk*K_BEAM + b2], s); }
        // top-10 with destructive exclusion (cells of beam b2 owned exclusively by this wave)
        #pragma unroll
        for (int pick = 0; pick < 10; ++pick) {
          float bv = -3e38f; int bi = 0x7ffffff0;
          for (int vl = lane; vl < vn; vl += 64) {
            float val = sh_lg[vl*K_BEAM + b2];
            if (val > bv || (val == bv && vl < bi)) { bv = val; bi = vl; }
          }
          wave_argmax_f(bv, bi);
          bv = __shfl(bv, 0, 64); bi = __shfl(bi, 0, 64);
          int wi = min(max(bi, 0), vn - 1);
          if (lane == 0) {
            stg_f(&cvv[(blk*K_BEAM + b2)*10 + pick], bv);
            stg_i(&cii[(blk*K_BEAM + b2)*10 + pick], v0 + wi);
          }
          if (bi >= 0 && bi < vn && (bi & 63) == lane) sh_lg[bi*K_BEAM + b2] = -3e38f;
        }
      }
    }
    gbar(bar, blk, tid, ++ep);

    // =================== PHASE SEL: blocks 0..9, beam j = blk — per-beam top-10 of 2560 ===================
    if (blk < K_BEAM) {
      const int j = blk;
      const int par = step & 1;
      const float* mcur = ws + (par == 0 ? META_B_F : META_A_F);   // META written this step
      const double scj = ldg_d(&((const double*)(mcur + M_SC))[j]);
      const int finj   = ldg_i(&((const int*)(mcur + M_FIN))[j]);
      const bool masked = finj || (step == 0 && j > 0);

      if (wv == 0) {
        double m = -1e300, s = 0.0;
        for (int c = lane; c < NBLK; c += 64) {
          double mc  = ldg_d(&((const double*)(ws + LSEM_F))[c*K_BEAM + j]);
          double sc2 = ldg_d(&((const double*)(ws + LSES_F))[c*K_BEAM + j]);
          double nm = fmax(m, mc);
          s = s*exp(m - nm) + sc2*exp(mc - nm); m = nm;
        }
        wave_merge_ms_d(m, s);
        if (lane == 0) sh_base = scj - (m + log(s));
      }
      __syncthreads();
      const double base = sh_base;

      // each wave: local top-10 over its 320 candidates (2560 total = NBLK*10)
      float rv[5]; int ri[5];
      #pragma unroll
      for (int k = 0; k < 5; ++k) {
        int c = wv*320 + 64*k + lane;
        int blkc = c / 10, p = c - blkc*10;
        int idx = (blkc*K_BEAM + j)*10 + p;
        rv[k] = ldg_f(&(ws + CANDV_F)[idx]);
        ri[k] = ldg_i(&((const int*)(ws + CANDI_F))[idx]);
      }
      #pragma unroll
      for (int pick = 0; pick < 10; ++pick) {
        double lv = -1e301; int li = 0x7ffffff0;
        if (!masked) {
          #pragma unroll
          for (int k = 0; k < 5; ++k) {
            double val = base + (double)rv[k];
            int v = ri[k];
            if (val > lv || (val == lv && v < li)) { lv = val; li = v; }
          }
        }
        #pragma unroll
        for (int off = 32; off > 0; off >>= 1) {
          double ov = __shfl_down(lv, off, 64);
          int    oi = __shfl_down(li, off, 64);
          if (ov > lv || (ov == lv && oi < li)) { lv = ov; li = oi; }
        }
        lv = __shfl(lv, 0, 64); li = __shfl(li, 0, 64);
        if (!masked) {
          #pragma unroll
          for (int k = 0; k < 5; ++k) if (ri[k] == li) rv[k] = -3e38f;  // destructive exclude
        }
        if (lane == 0) { sh_wtv[wv*10 + pick] = lv; sh_wti[wv*10 + pick] = li; }
      }
      __syncthreads();

      // wave 0: merge 80 -> 10, write global B10
      if (wv == 0) {
        double av = (lane < 80) ? sh_wtv[lane] : -1e305;
        int    ai = (lane < 80) ? sh_wti[lane] : 0x7fffffff;
        const int c1 = lane + 64;
        double bv2 = (c1 < 80) ? sh_wtv[c1] : -1e305;
        int    bi2 = (c1 < 80) ? sh_wti[c1] : 0x7fffffff;
        #pragma unroll
        for (int pick = 0; pick < 10; ++pick) {
          bool tb = (bv2 > av) || (bv2 == av && bi2 < ai);
          double lv = tb ? bv2 : av;
          int    li = tb ? bi2 : ai;
          int    ls = tb ? c1  : lane;
          #pragma unroll
          for (int off = 32; off > 0; off >>= 1) {
            double ov = __shfl_down(lv, off, 64);
            int    oi = __shfl_down(li, off, 64);
            int    os = __shfl_down(ls, off, 64);
            if (ov > lv || (ov == lv && oi < li)) { lv = ov; li = oi; ls = os; }
          }
          ls = __shfl(ls, 0, 64);
          if (ls == lane) { av  = -1e305; ai  = 0x7fffffff; }
          if (ls == c1)   { bv2 = -1e305; bi2 = 0x7fffffff; }
          if (lane == 0) {
            double outv; int outf;
            if (finj) {
              outv = (pick == 0) ? scj : -1e301;
              outf = (pick == 0) ? (j*V_SZ + EOS_TOK) : 0x7ffffff0;
            } else if (step == 0 && j > 0) {
              outv = -1e301; outf = 0x7ffffff0;
            } else {
              outv = lv;
              outf = j*V_SZ + min(max(li, 0), V_SZ - 1);
            }
            stg_d(&((double*)(ws + B10V_F))[j*10 + pick], outv);
            stg_i(&((int*)(ws + B10F_F))[j*10 + pick], outf);
          }
        }
      }
    }
    gbar(bar, blk, tid, ++ep);
  } // step loop

  // =================== FINAL: block 0 — last selection + gather + output ===================
  if (blk == 0) {
    __syncthreads();
    if (wv == 0) merge100(ws, sh_selv, sh_self, lane);
    __syncthreads();
    const float* mA = ws + META_A_F;              // dst of step 29 (odd -> A)
    const int* seqA = (const int*)(mA + M_SEQ);
    if (tid < K_BEAM) {
      int f = sh_self[tid];
      int pb = f / V_SZ, tk2 = f - pb*V_SZ;
      sh_fpb[tid]  = min(max(pb, 0), K_BEAM - 1);
      sh_ftok[tid] = min(max(tk2, 0), V_SZ - 1);
    }
    __syncthreads();
    for (int t = tid; t < K_BEAM*SEQ_LEN; t += NTHR) {
      int j2 = t / SEQ_LEN, p = t - j2*SEQ_LEN;
      sh_seqF[t] = (p == MAXLEN) ? sh_ftok[j2] : ldg_i(&seqA[sh_fpb[j2]*SEQ_LEN + p]);
    }
    __syncthreads();
    if (tid < K_BEAM) {
      int first = -1;
      for (int p = 1; p <= MAXLEN; ++p)
        if (sh_seqF[tid*SEQ_LEN + p] == EOS_TOK) { first = p - 1; break; }
      double len = (first >= 0) ? (double)(first + 2) : (double)(MAXLEN + 2);
      double scv = sh_selv[tid];
      out[K_BEAM*SEQ_LEN + tid] = (float)scv;
      out[K_BEAM*SEQ_LEN + K_BEAM + tid] = (float)(scv / pow(len, 1.2));
    }
    for (int t = tid; t < K_BEAM*SEQ_LEN; t += NTHR) out[t] = (float)sh_seqF[t];
  }
}

// ---------------- host ----------------
extern "C" void kernel_launch(void* const* d_in, const int* in_sizes, int n_in,
                              void* d_out, int out_size, void* d_ws, size_t ws_size,
                              hipStream_t stream) {
  (void)in_sizes; (void)n_in; (void)out_size; (void)ws_size;
  const float* enc_key    = (const float*)d_in[0];
  const float* enc_values = (const float*)d_in[1];
  const float* maskp      = (const float*)d_in[2];
  const float* embedding  = (const float*)d_in[3];
  const float* W_ih1      = (const float*)d_in[4];
  const float* W_hh1      = (const float*)d_in[5];
  const float* b_ih1      = (const float*)d_in[6];
  const float* b_hh1      = (const float*)d_in[7];
  const float* W_ih2      = (const float*)d_in[8];
  const float* W_hh2      = (const float*)d_in[9];
  const float* b_ih2      = (const float*)d_in[10];
  const float* b_hh2      = (const float*)d_in[11];
  const float* Wq         = (const float*)d_in[12];
  const float* bq         = (const float*)d_in[13];
  const float* Wc         = (const float*)d_in[14];
  const float* bc         = (const float*)d_in[15];
  float* ws  = (float*)d_ws;
  float* out = (float*)d_out;

  // zero the barrier epoch region (graph-capturable; re-runs on each graph replay)
  hipMemsetAsync((char*)d_ws + (size_t)BAR_F * 4, 0, BAR_BYTES, stream);

  void* args[] = { (void*)&ws, (void*)&out,
                   (void*)&enc_key, (void*)&enc_values, (void*)&maskp, (void*)&embedding,
                   (void*)&W_ih1, (void*)&W_hh1, (void*)&b_ih1, (void*)&b_hh1,
                   (void*)&W_ih2, (void*)&W_hh2, (void*)&b_ih2, (void*)&b_hh2,
                   (void*)&Wq, (void*)&bq, (void*)&Wc, (void*)&bc };
  hipLaunchCooperativeKernel((const void*)beam_fused, dim3(NBLK), dim3(NTHR), args, 0, stream);
}